// Round 8
// baseline (589.579 us; speedup 1.0000x reference)
//
#include <hip/hip_runtime.h>
#include <hip/hip_fp16.h>
#include <stdint.h>

static constexpr int N_NODES = 200000;
static constexpr int N_EDGES = 6400000;
static constexpr int F_INC = 128;
static constexpr int F1 = 12;
static constexpr int F2 = 24;
static constexpr int HS1_STRIDE = 16; // halfs -> 32 B rows
static constexpr int HS2_STRIDE = 32; // halfs -> 64 B rows
static constexpr int NBUCK = (N_NODES + 255) / 256; // 782
static constexpr int NT = 7;          // source tiles of 32768 nodes (src >> 15)
static constexpr int KPB = 8;         // key slots per dest (7 tiles + 1 end)
static constexpr int CHUNK = 8192;    // edges per hist/scatter block
static constexpr int NBLK = (N_EDGES + CHUNK - 1) / CHUNK; // 782

__device__ __forceinline__ int clampN(int v) {
    return min(max(v, 0), N_NODES - 1);
}

// ---- K1: per-block bucket histogram -> hist2d[b][k] (coalesced row write) ----
__global__ __launch_bounds__(1024) void hist_pass(const int* __restrict__ col,
                                                  int* __restrict__ hist2d) {
    __shared__ int h[NBUCK];
    int t = threadIdx.x, b = blockIdx.x;
    for (int i = t; i < NBUCK; i += 1024) h[i] = 0;
    __syncthreads();
    int base4 = (b * CHUNK) >> 2;
    const int4* col4 = (const int4*)col;
#pragma unroll
    for (int it = 0; it < CHUNK / 4096; it++) {
        int q = base4 + it * 1024 + t;
        if (q < N_EDGES / 4) { // N_EDGES % 4 == 0, no straddle
            int4 c = col4[q];
            atomicAdd(&h[clampN(c.x) >> 8], 1);
            atomicAdd(&h[clampN(c.y) >> 8], 1);
            atomicAdd(&h[clampN(c.z) >> 8], 1);
            atomicAdd(&h[clampN(c.w) >> 8], 1);
        }
    }
    __syncthreads();
    for (int k = t; k < NBUCK; k += 1024)
        hist2d[(size_t)b * NBUCK + k] = h[k];
}

// ---- K2a: per-bucket exclusive prefix over blocks (in place) + bucket total ----
__global__ __launch_bounds__(256) void colscan(int* __restrict__ hist2d,
                                               int* __restrict__ bcnt) {
    __shared__ int ps[256];
    int k = blockIdx.x, t = threadIdx.x;
    int vals[4];
    int sum = 0;
#pragma unroll
    for (int j = 0; j < 4; j++) {
        int b = t * 4 + j;
        vals[j] = (b < NBLK) ? hist2d[(size_t)b * NBUCK + k] : 0;
        sum += vals[j];
    }
    ps[t] = sum;
    int mine = sum;
    for (int off = 1; off < 256; off <<= 1) {
        __syncthreads();
        int a = (t >= off) ? ps[t - off] : 0;
        __syncthreads();
        ps[t] += a;
    }
    __syncthreads();
    int excl = ps[t] - mine;
#pragma unroll
    for (int j = 0; j < 4; j++) {
        int b = t * 4 + j;
        if (b < NBLK) hist2d[(size_t)b * NBUCK + k] = excl;
        excl += vals[j];
    }
    if (t == 255) bcnt[k] = ps[255];
}

// ---- K2b: scan bucket totals -> bbase (NBUCK+1) ----
__global__ __launch_bounds__(1024) void bucket_scan(const int* __restrict__ bcnt,
                                                    int* __restrict__ bbase) {
    __shared__ int tmp[1024];
    int t = threadIdx.x;
    int v = (t < NBUCK) ? bcnt[t] : 0;
    tmp[t] = v;
    for (int off = 1; off < 1024; off <<= 1) {
        __syncthreads();
        int a = (t >= off) ? tmp[t - off] : 0;
        __syncthreads();
        tmp[t] += a;
    }
    __syncthreads();
    if (t < NBUCK) bbase[t] = tmp[t] - v;
    if (t == 0) bbase[NBUCK] = N_EDGES;
}

// ---- K3: scatter with deterministic per-(block,bucket) bases ----
__global__ __launch_bounds__(1024) void scatter2(const int* __restrict__ row,
                                                 const int* __restrict__ col,
                                                 const int* __restrict__ bbase,
                                                 const int* __restrict__ hist2d,
                                                 int* __restrict__ tmpArr) {
    __shared__ int cur[NBUCK];
    int t = threadIdx.x, b = blockIdx.x;
    for (int k = t; k < NBUCK; k += 1024)
        cur[k] = bbase[k] + hist2d[(size_t)b * NBUCK + k];
    __syncthreads();
    int base4 = (b * CHUNK) >> 2;
    const int4* col4 = (const int4*)col;
    const int4* row4 = (const int4*)row;
#pragma unroll
    for (int it = 0; it < CHUNK / 4096; it++) {
        int q = base4 + it * 1024 + t;
        if (q < N_EDGES / 4) {
            int4 c4 = col4[q];
            int4 r4 = row4[q];
            int cc[4] = {c4.x, c4.y, c4.z, c4.w};
            int rr[4] = {r4.x, r4.y, r4.z, r4.w};
#pragma unroll
            for (int u = 0; u < 4; u++) {
                int c = clampN(cc[u]);
                int r = clampN(rr[u]);
                int p = atomicAdd(&cur[c >> 8], 1);
                tmpArr[p] = (r << 8) | (c & 255);
            }
        }
    }
}

// ---- pass C: per-bucket counting sort by (dcol, src_tile) + degree-balancing perm ----
__global__ __launch_bounds__(256) void bucket_fill(const int* __restrict__ tmpArr,
                                                   const int* __restrict__ bbase,
                                                   unsigned short* __restrict__ offs2,
                                                   float* __restrict__ dinv,
                                                   int* __restrict__ csr,
                                                   unsigned char* __restrict__ perm) {
    __shared__ int hist[256 * KPB]; // 8 KB
    __shared__ int part[256];
    int b = blockIdx.x, t = threadIdx.x;
    int node0 = b << 8;
    int s = bbase[b], e = bbase[b + 1];
    for (int k = t; k < 256 * KPB; k += 256) hist[k] = 0;
    __syncthreads();
    for (int i = s + t; i < e; i += 256) {
        int en = tmpArr[i];
        int key = ((en & 255) << 3) | ((en >> 8) >> 15);
        atomicAdd(&hist[key], 1);
    }
    __syncthreads();
    // thread t == dest t: serial exclusive scan of its 8 key slots
    int base = t << 3;
    int ex[KPB];
    int sum = 0;
#pragma unroll
    for (int j = 0; j < KPB; j++) { ex[j] = sum; sum += hist[base + j]; }
    part[t] = sum;
    int nn = min(256, N_NODES - node0);
    if (t < nn) dinv[node0 + t] = rsqrtf((float)(sum + 1));
    // block exclusive scan over part
    int mine = sum;
    for (int off = 1; off < 256; off <<= 1) {
        __syncthreads();
        int a = (t >= off) ? part[t - off] : 0;
        __syncthreads();
        part[t] += a;
    }
    __syncthreads();
    int chunk0 = part[t] - mine; // exclusive prefix for this dest
#pragma unroll
    for (int j = 0; j < KPB; j++) hist[base + j] = chunk0 + ex[j];
    __syncthreads();
    // offs2: bucket-local u16 starts (slot j = start of tile j; slot 7 = end)
    for (int k = t; k < 256 * KPB; k += 256)
        offs2[((size_t)b << 11) + k] = (unsigned short)hist[k];
    __syncthreads();
    // scatter: hist reused as cursors
    for (int i = s + t; i < e; i += 256) {
        int en = tmpArr[i];
        int src = en >> 8;
        int key = ((en & 255) << 3) | (src >> 15);
        int p = atomicAdd(&hist[key], 1);
        csr[s + p] = src;
    }
    // ---- degree-balancing permutation: counting sort dests by degree ----
    __syncthreads(); // cursor use of hist done
    part[t] = 0;
    __syncthreads();
    int dcl = min(sum, 255);
    atomicAdd(&part[dcl], 1);
    __syncthreads();
    int dcount = part[t];
    hist[t] = dcount; // inclusive scan over degree counts in hist[0..255]
    for (int off = 1; off < 256; off <<= 1) {
        __syncthreads();
        int a = (t >= off) ? hist[t - off] : 0;
        __syncthreads();
        hist[t] += a;
    }
    __syncthreads();
    part[t] = hist[t] - dcount; // exclusive prefix = cursor base per degree class
    __syncthreads();
    int rank = atomicAdd(&part[dcl], 1);
    perm[(b << 8) + rank] = (unsigned char)t;
}

// ---- hs1[v] = (x[v] @ W1) * dinv[v], fp16, 32 B rows ----
__global__ __launch_bounds__(256) void gemm1(const float* __restrict__ x,
                                             const float* __restrict__ W1,
                                             const float* __restrict__ dinv,
                                             __half* __restrict__ hs1) {
    __shared__ float Wl[F_INC * F1];
    for (int i = threadIdx.x; i < F_INC * F1; i += 256) Wl[i] = W1[i];
    __syncthreads();
    int v = blockIdx.x * 256 + threadIdx.x;
    if (v >= N_NODES) return;
    float acc[F1];
#pragma unroll
    for (int f = 0; f < F1; f++) acc[f] = 0.f;
    const float4* xr = (const float4*)(x + (size_t)v * F_INC);
    for (int k4 = 0; k4 < F_INC / 4; k4++) {
        float4 xv = xr[k4];
        int kb = k4 * 4;
#pragma unroll
        for (int f = 0; f < F1; f++) {
            acc[f] += xv.x * Wl[(kb + 0) * F1 + f] + xv.y * Wl[(kb + 1) * F1 + f] +
                      xv.z * Wl[(kb + 2) * F1 + f] + xv.w * Wl[(kb + 3) * F1 + f];
        }
    }
    float dv = dinv[v];
    int w[6];
#pragma unroll
    for (int j = 0; j < 6; j++) {
        __half2 p = __floats2half2_rn(acc[2 * j] * dv, acc[2 * j + 1] * dv);
        w[j] = *(int*)&p;
    }
    __half* rowp = hs1 + (size_t)v * HS1_STRIDE;
    ((int4*)rowp)[0] = make_int4(w[0], w[1], w[2], w[3]);
    ((int2*)rowp)[2] = make_int2(w[4], w[5]);
}

__device__ __forceinline__ void acc_row1(float* acc, const __half* rowp) {
    int4 a = ((const int4*)rowp)[0];
    int2 b = ((const int2*)rowp)[2];
    int ws[6] = {a.x, a.y, a.z, a.w, b.x, b.y};
#pragma unroll
    for (int j = 0; j < 6; j++) {
        float2 t = __half22float2(*(__half2*)&ws[j]);
        acc[2 * j] += t.x;
        acc[2 * j + 1] += t.y;
    }
}

__device__ __forceinline__ void acc_row2(float* acc, const __half* rowp) {
    int4 a = ((const int4*)rowp)[0];
    int4 b = ((const int4*)rowp)[1];
    int4 c = ((const int4*)rowp)[2];
    int ws[12] = {a.x, a.y, a.z, a.w, b.x, b.y, b.z, b.w, c.x, c.y, c.z, c.w};
#pragma unroll
    for (int j = 0; j < 12; j++) {
        float2 t = __half22float2(*(__half2*)&ws[j]);
        acc[2 * j] += t.x;
        acc[2 * j + 1] += t.y;
    }
}

__device__ __forceinline__ void unpack_offsets(int* of, const unsigned short* offs2, int v) {
    const int4* p = (const int4*)(offs2 + ((size_t)v << 3));
    int4 a = p[0];
    of[0] = a.x & 0xffff; of[1] = (a.x >> 16) & 0xffff;
    of[2] = a.y & 0xffff; of[3] = (a.y >> 16) & 0xffff;
    of[4] = a.z & 0xffff; of[5] = (a.z >> 16) & 0xffff;
    of[6] = a.w & 0xffff; of[7] = (a.w >> 16) & 0xffff;
}

// ---- layer-1 aggregate: software-pipelined gather (2-stage index lookahead),
//      group=8, A/B register double-buffer. Breaks the idx->row serial chain. ----
#define LOADI1(IX, pos) do { \
    int4 c0_ = *(const int4*)(csr + (pos)); \
    int4 c1_ = *(const int4*)(csr + (pos) + 4); \
    IX[0] = c0_.x; IX[1] = c0_.y; IX[2] = c0_.z; IX[3] = c0_.w; \
    IX[4] = c1_.x; IX[5] = c1_.y; IX[6] = c1_.z; IX[7] = c1_.w; \
} while (0)
#define LOADR1(RA, RB, IX) do { \
    _Pragma("unroll") for (int u_ = 0; u_ < 8; u_++) { \
        const __half* rp_ = hs1 + (size_t)IX[u_] * HS1_STRIDE; \
        RA[u_] = ((const int4*)rp_)[0]; \
        RB[u_] = ((const int2*)rp_)[2]; \
    } \
} while (0)
#define ACCG1(RA, RB) do { \
    _Pragma("unroll") for (int u_ = 0; u_ < 8; u_++) { \
        int ws_[6] = {RA[u_].x, RA[u_].y, RA[u_].z, RA[u_].w, RB[u_].x, RB[u_].y}; \
        _Pragma("unroll") for (int j_ = 0; j_ < 6; j_++) { \
            float2 f2_ = __half22float2(*(__half2*)&ws_[j_]); \
            acc[2 * j_] += f2_.x; acc[2 * j_ + 1] += f2_.y; \
        } \
    } \
} while (0)

__global__ __launch_bounds__(256, 3) void agg1(const __half* __restrict__ hs1,
                                               const unsigned short* __restrict__ offs2,
                                               const int* __restrict__ csr,
                                               const int* __restrict__ bbase,
                                               const float* __restrict__ dinv,
                                               const unsigned char* __restrict__ perm,
                                               const float* __restrict__ W2,
                                               const float* __restrict__ b1,
                                               __half* __restrict__ hs2) {
    __shared__ float Wl[F1 * F2];
    __shared__ float bl[F1];
    int t = threadIdx.x, b = blockIdx.x;
    for (int i = t; i < F1 * F2; i += 256) Wl[i] = W2[i];
    if (t < F1) bl[t] = b1[t];
    __syncthreads();
    int t2 = perm[(b << 8) + t]; // lanes get degree-similar dests
    int v = (b << 8) + t2;
    bool valid = v < N_NODES;
    int bb = bbase[b];
    float acc[F1];
#pragma unroll
    for (int f = 0; f < F1; f++) acc[f] = 0.f;
    if (valid) acc_row1(acc, hs1 + (size_t)v * HS1_STRIDE); // self loop
    int of[KPB];
    unpack_offsets(of, offs2, v);
    int i = bb + of[0], e = bb + of[7]; // contiguous, tile-sorted (ascending src)
    for (; i < e && (i & 3); ++i)
        acc_row1(acc, hs1 + (size_t)csr[i] * HS1_STRIDE);
    int n8 = (e - i) >> 3;
    if (n8 > 0) {
        int ixa[8], ixb[8];
        int4 raA[8], raB[8];
        int2 rbA[8], rbB[8];
        LOADI1(ixa, i);
        if (n8 >= 2) LOADI1(ixb, i + 8);
        LOADR1(raA, rbA, ixa);
        int g = 0;
        while (true) {
            if (g + 1 < n8) {
                LOADR1(raB, rbB, ixb);       // wait ixb (FIFO => raA/rbA done)
                if (g + 2 < n8) LOADI1(ixa, i + (g + 2) * 8);
                ACCG1(raA, rbA);
                ++g;
                if (g + 1 < n8) {
                    LOADR1(raA, rbA, ixa);
                    if (g + 2 < n8) LOADI1(ixb, i + (g + 2) * 8);
                    ACCG1(raB, rbB);
                    ++g;
                } else { ACCG1(raB, rbB); ++g; break; }
            } else { ACCG1(raA, rbA); ++g; break; }
        }
        i += n8 * 8;
    }
    for (; i < e; ++i)
        acc_row1(acc, hs1 + (size_t)csr[i] * HS1_STRIDE);
    if (!valid) return;
    float dv = dinv[v];
    float o[F1];
#pragma unroll
    for (int f = 0; f < F1; f++) o[f] = fmaxf(dv * acc[f] + bl[f], 0.f);
    float h2[F2];
#pragma unroll
    for (int g = 0; g < F2; g++) {
        float sum = 0.f;
#pragma unroll
        for (int f = 0; f < F1; f++) sum += o[f] * Wl[f * F2 + g];
        h2[g] = dv * sum;
    }
    int w[12];
#pragma unroll
    for (int j = 0; j < 12; j++) {
        __half2 p = __floats2half2_rn(h2[2 * j], h2[2 * j + 1]);
        w[j] = *(int*)&p;
    }
    int4* op = (int4*)(hs2 + (size_t)v * HS2_STRIDE);
    op[0] = make_int4(w[0], w[1], w[2], w[3]);
    op[1] = make_int4(w[4], w[5], w[6], w[7]);
    op[2] = make_int4(w[8], w[9], w[10], w[11]);
}

// ---- layer-2 aggregate: software-pipelined gather, group=4 (96 row-VGPRs dbuf) ----
#define LOADR2(P0, P1, P2, IX) do { \
    const int4* rp0_ = (const int4*)(hs2 + (size_t)(IX).x * HS2_STRIDE); \
    const int4* rp1_ = (const int4*)(hs2 + (size_t)(IX).y * HS2_STRIDE); \
    const int4* rp2_ = (const int4*)(hs2 + (size_t)(IX).z * HS2_STRIDE); \
    const int4* rp3_ = (const int4*)(hs2 + (size_t)(IX).w * HS2_STRIDE); \
    P0[0] = rp0_[0]; P1[0] = rp0_[1]; P2[0] = rp0_[2]; \
    P0[1] = rp1_[0]; P1[1] = rp1_[1]; P2[1] = rp1_[2]; \
    P0[2] = rp2_[0]; P1[2] = rp2_[1]; P2[2] = rp2_[2]; \
    P0[3] = rp3_[0]; P1[3] = rp3_[1]; P2[3] = rp3_[2]; \
} while (0)
#define ACCG2(P0, P1, P2) do { \
    _Pragma("unroll") for (int u_ = 0; u_ < 4; u_++) { \
        int ws_[12] = {P0[u_].x, P0[u_].y, P0[u_].z, P0[u_].w, \
                       P1[u_].x, P1[u_].y, P1[u_].z, P1[u_].w, \
                       P2[u_].x, P2[u_].y, P2[u_].z, P2[u_].w}; \
        _Pragma("unroll") for (int j_ = 0; j_ < 12; j_++) { \
            float2 f2_ = __half22float2(*(__half2*)&ws_[j_]); \
            acc[2 * j_] += f2_.x; acc[2 * j_ + 1] += f2_.y; \
        } \
    } \
} while (0)

__global__ __launch_bounds__(256, 3) void agg2(const __half* __restrict__ hs2,
                                               const unsigned short* __restrict__ offs2,
                                               const int* __restrict__ csr,
                                               const int* __restrict__ bbase,
                                               const float* __restrict__ dinv,
                                               const unsigned char* __restrict__ perm,
                                               const float* __restrict__ b2,
                                               const float* __restrict__ Wf1,
                                               const float* __restrict__ bf1,
                                               const float* __restrict__ Wf2,
                                               const float* __restrict__ bf2,
                                               float* __restrict__ out) {
    __shared__ float W1s[F2 * 32];
    __shared__ float W2s[32 * 2];
    __shared__ float b2s[F2], b1s[32], bfs[2];
    int t = threadIdx.x, b = blockIdx.x;
    for (int i = t; i < F2 * 32; i += 256) W1s[i] = Wf1[i];
    if (t < 64) W2s[t] = Wf2[t];
    if (t < F2) b2s[t] = b2[t];
    if (t < 32) b1s[t] = bf1[t];
    if (t < 2) bfs[t] = bf2[t];
    __syncthreads();
    int t2 = perm[(b << 8) + t];
    int v = (b << 8) + t2;
    bool valid = v < N_NODES;
    int bb = bbase[b];
    float acc[F2];
#pragma unroll
    for (int f = 0; f < F2; f++) acc[f] = 0.f;
    if (valid) acc_row2(acc, hs2 + (size_t)v * HS2_STRIDE); // self loop
    int of[KPB];
    unpack_offsets(of, offs2, v);
    int i = bb + of[0], e = bb + of[7];
    for (; i < e && (i & 3); ++i)
        acc_row2(acc, hs2 + (size_t)csr[i] * HS2_STRIDE);
    int n4 = (e - i) >> 2;
    if (n4 > 0) {
        int4 ixa, ixb;
        int4 A0[4], A1[4], A2[4], B0[4], B1[4], B2[4];
        ixa = *(const int4*)(csr + i);
        if (n4 >= 2) ixb = *(const int4*)(csr + i + 4);
        LOADR2(A0, A1, A2, ixa);
        int g = 0;
        while (true) {
            if (g + 1 < n4) {
                LOADR2(B0, B1, B2, ixb);     // wait ixb (FIFO => A rows done)
                if (g + 2 < n4) ixa = *(const int4*)(csr + i + (g + 2) * 4);
                ACCG2(A0, A1, A2);
                ++g;
                if (g + 1 < n4) {
                    LOADR2(A0, A1, A2, ixa);
                    if (g + 2 < n4) ixb = *(const int4*)(csr + i + (g + 2) * 4);
                    ACCG2(B0, B1, B2);
                    ++g;
                } else { ACCG2(B0, B1, B2); ++g; break; }
            } else { ACCG2(A0, A1, A2); ++g; break; }
        }
        i += n4 * 4;
    }
    for (; i < e; ++i)
        acc_row2(acc, hs2 + (size_t)csr[i] * HS2_STRIDE);
    if (!valid) return;
    float dv = dinv[v];
    float o2[F2];
#pragma unroll
    for (int f = 0; f < F2; f++) o2[f] = fmaxf(dv * acc[f] + b2s[f], 0.f);
    float c0 = bfs[0], c1 = bfs[1];
#pragma unroll
    for (int g = 0; g < 32; g++) {
        float sum = b1s[g];
#pragma unroll
        for (int f = 0; f < F2; f++) sum += o2[f] * W1s[f * 32 + g];
        sum = fmaxf(sum, 0.f);
        c0 += sum * W2s[2 * g + 0];
        c1 += sum * W2s[2 * g + 1];
    }
    float2 r; r.x = c0; r.y = c1;
    ((float2*)out)[v] = r;
}

extern "C" void kernel_launch(void* const* d_in, const int* in_sizes, int n_in,
                              void* d_out, int out_size, void* d_ws, size_t ws_size,
                              hipStream_t stream) {
    const float* x = (const float*)d_in[0];
    const int* erow = (const int*)d_in[1]; // edge_index delivered as int32
    const int* ecol = erow + N_EDGES;
    const float* W1 = (const float*)d_in[2];
    const float* b1 = (const float*)d_in[3];
    const float* W2 = (const float*)d_in[4];
    const float* b2 = (const float*)d_in[5];
    const float* Wf1 = (const float*)d_in[6];
    const float* bf1 = (const float*)d_in[7];
    const float* Wf2 = (const float*)d_in[8];
    const float* bf2 = (const float*)d_in[9];
    float* out = (float*)d_out;

    char* w = (char*)d_ws;
    auto alloc = [&](size_t bytes) -> char* {
        char* p = w;
        w += (bytes + 255) / 256 * 256;
        return p;
    };
    int* bcnt = (int*)alloc((size_t)NBUCK * 4);
    int* bbase = (int*)alloc((size_t)(NBUCK + 1) * 4);
    int* hist2d = (int*)alloc((size_t)NBLK * NBUCK * 4); // 2.45 MB
    float* dinv = (float*)alloc((size_t)N_NODES * 4);
    unsigned char* perm = (unsigned char*)alloc((size_t)NBUCK * 256); // 200 KB
    unsigned short* offs2 = (unsigned short*)alloc((size_t)NBUCK * 256 * KPB * 2 + 256); // 3.2 MB (+pad)
    int* csr = (int*)alloc((size_t)N_EDGES * 4); // 25.6 MB
    // union: tmpArr (25.6 MB) dead after bucket_fill; hs1 (6.4) + hs2 (12.8) after
    size_t hs1_bytes = (size_t)N_NODES * HS1_STRIDE * 2;
    char* uni = alloc((size_t)N_EDGES * 4);
    int* tmpArr = (int*)uni;
    __half* hs1 = (__half*)uni;
    __half* hs2 = (__half*)(uni + hs1_bytes);

    const int nodeGrid = (N_NODES + 255) / 256;

    hipLaunchKernelGGL(hist_pass, dim3(NBLK), dim3(1024), 0, stream, ecol, hist2d);
    hipLaunchKernelGGL(colscan, dim3(NBUCK), dim3(256), 0, stream, hist2d, bcnt);
    hipLaunchKernelGGL(bucket_scan, dim3(1), dim3(1024), 0, stream, bcnt, bbase);
    hipLaunchKernelGGL(scatter2, dim3(NBLK), dim3(1024), 0, stream, erow, ecol, bbase, hist2d, tmpArr);
    hipLaunchKernelGGL(bucket_fill, dim3(NBUCK), dim3(256), 0, stream, tmpArr, bbase, offs2, dinv, csr, perm);
    hipLaunchKernelGGL(gemm1, dim3(nodeGrid), dim3(256), 0, stream, x, W1, dinv, hs1);
    hipLaunchKernelGGL(agg1, dim3(NBUCK), dim3(256), 0, stream,
                       hs1, offs2, csr, bbase, dinv, perm, W2, b1, hs2);
    hipLaunchKernelGGL(agg2, dim3(NBUCK), dim3(256), 0, stream,
                       hs2, offs2, csr, bbase, dinv, perm, b2, Wf1, bf1, Wf2, bf2, out);
}

// Round 9
// 502.155 us; speedup vs baseline: 1.1741x; 1.1741x over previous
//
#include <hip/hip_runtime.h>
#include <hip/hip_fp16.h>
#include <stdint.h>

static constexpr int N_NODES = 200000;
static constexpr int N_EDGES = 6400000;
static constexpr int F_INC = 128;
static constexpr int F1 = 12;
static constexpr int F2 = 24;
static constexpr int HS1_STRIDE = 16; // halfs -> 32 B rows
static constexpr int HS2_STRIDE = 32; // halfs -> 64 B rows
static constexpr int NBUCK = (N_NODES + 255) / 256; // 782
static constexpr int NT = 13;         // source tiles of 16384 nodes (src >> 14) -> 1 MB hs2 tiles
static constexpr int KPB = 16;        // key slots per dest (13 tiles + end sentinel)
static constexpr int CHUNK = 8192;    // edges per hist/scatter block
static constexpr int NBLK = (N_EDGES + CHUNK - 1) / CHUNK; // 782
static constexpr int CSRCAP = 9216;   // LDS csr staging cap (mean bucket 8186, +11 sigma)

__device__ __forceinline__ int clampN(int v) {
    return min(max(v, 0), N_NODES - 1);
}

// ---- K1: per-block bucket histogram -> hist2d[b][k] (coalesced row write) ----
__global__ __launch_bounds__(1024) void hist_pass(const int* __restrict__ col,
                                                  int* __restrict__ hist2d) {
    __shared__ int h[NBUCK];
    int t = threadIdx.x, b = blockIdx.x;
    for (int i = t; i < NBUCK; i += 1024) h[i] = 0;
    __syncthreads();
    int base4 = (b * CHUNK) >> 2;
    const int4* col4 = (const int4*)col;
#pragma unroll
    for (int it = 0; it < CHUNK / 4096; it++) {
        int q = base4 + it * 1024 + t;
        if (q < N_EDGES / 4) { // N_EDGES % 4 == 0, no straddle
            int4 c = col4[q];
            atomicAdd(&h[clampN(c.x) >> 8], 1);
            atomicAdd(&h[clampN(c.y) >> 8], 1);
            atomicAdd(&h[clampN(c.z) >> 8], 1);
            atomicAdd(&h[clampN(c.w) >> 8], 1);
        }
    }
    __syncthreads();
    for (int k = t; k < NBUCK; k += 1024)
        hist2d[(size_t)b * NBUCK + k] = h[k];
}

// ---- K2a: per-bucket exclusive prefix over blocks (in place) + bucket total ----
__global__ __launch_bounds__(256) void colscan(int* __restrict__ hist2d,
                                               int* __restrict__ bcnt) {
    __shared__ int ps[256];
    int k = blockIdx.x, t = threadIdx.x;
    int vals[4];
    int sum = 0;
#pragma unroll
    for (int j = 0; j < 4; j++) {
        int b = t * 4 + j;
        vals[j] = (b < NBLK) ? hist2d[(size_t)b * NBUCK + k] : 0;
        sum += vals[j];
    }
    ps[t] = sum;
    int mine = sum;
    for (int off = 1; off < 256; off <<= 1) {
        __syncthreads();
        int a = (t >= off) ? ps[t - off] : 0;
        __syncthreads();
        ps[t] += a;
    }
    __syncthreads();
    int excl = ps[t] - mine;
#pragma unroll
    for (int j = 0; j < 4; j++) {
        int b = t * 4 + j;
        if (b < NBLK) hist2d[(size_t)b * NBUCK + k] = excl;
        excl += vals[j];
    }
    if (t == 255) bcnt[k] = ps[255];
}

// ---- K2b: scan bucket totals -> bbase (NBUCK+1) ----
__global__ __launch_bounds__(1024) void bucket_scan(const int* __restrict__ bcnt,
                                                    int* __restrict__ bbase) {
    __shared__ int tmp[1024];
    int t = threadIdx.x;
    int v = (t < NBUCK) ? bcnt[t] : 0;
    tmp[t] = v;
    for (int off = 1; off < 1024; off <<= 1) {
        __syncthreads();
        int a = (t >= off) ? tmp[t - off] : 0;
        __syncthreads();
        tmp[t] += a;
    }
    __syncthreads();
    if (t < NBUCK) bbase[t] = tmp[t] - v;
    if (t == 0) bbase[NBUCK] = N_EDGES;
}

// ---- K3: scatter via LDS presort by bucket -> coalesced run writes.
//      Local counts derived from hist2d prefix diffs (no extra atomics). ----
__global__ __launch_bounds__(1024) void scatter2(const int* __restrict__ row,
                                                 const int* __restrict__ col,
                                                 const int* __restrict__ bbase,
                                                 const int* __restrict__ hist2d,
                                                 const int* __restrict__ bcnt,
                                                 int* __restrict__ tmpArr) {
    __shared__ int scan[1024];
    __shared__ int cur[NBUCK];
    __shared__ int gbase[NBUCK];
    __shared__ int ebufA[CHUNK]; // 32 KB packed records, bucket-sorted
    __shared__ int ebufB[CHUNK]; // 32 KB global dest addresses (monotone per run)
    int t = threadIdx.x, b = blockIdx.x;
    int myBase = 0, myCnt = 0;
    if (t < NBUCK) {
        myBase = hist2d[(size_t)b * NBUCK + t];
        int nxt = (b + 1 < NBLK) ? hist2d[(size_t)(b + 1) * NBUCK + t] : bcnt[t];
        myCnt = nxt - myBase;
    }
    scan[t] = myCnt;
    for (int off = 1; off < 1024; off <<= 1) {
        __syncthreads();
        int a = (t >= off) ? scan[t - off] : 0;
        __syncthreads();
        scan[t] += a;
    }
    __syncthreads();
    if (t < NBUCK) {
        int lexcl = scan[t] - myCnt;
        cur[t] = lexcl;
        gbase[t] = bbase[t] + myBase - lexcl;
    }
    __syncthreads();
    int base4 = (b * CHUNK) >> 2;
    const int4* col4 = (const int4*)col;
    const int4* row4 = (const int4*)row;
#pragma unroll
    for (int it = 0; it < CHUNK / 4096; it++) {
        int q = base4 + it * 1024 + t;
        if (q < N_EDGES / 4) {
            int4 c4 = col4[q];
            int4 r4 = row4[q];
            int cc[4] = {c4.x, c4.y, c4.z, c4.w};
            int rr[4] = {r4.x, r4.y, r4.z, r4.w};
#pragma unroll
            for (int u = 0; u < 4; u++) {
                int c = clampN(cc[u]);
                int r = clampN(rr[u]);
                int k = c >> 8;
                int p = atomicAdd(&cur[k], 1);
                ebufA[p] = (r << 8) | (c & 255);
                ebufB[p] = gbase[k] + p;
            }
        }
    }
    __syncthreads();
    int n = min(CHUNK, N_EDGES - b * CHUNK);
    for (int i = t; i < n; i += 1024)
        tmpArr[ebufB[i]] = ebufA[i]; // consecutive i -> consecutive addr within runs
}

// ---- pass C: per-bucket counting sort by (dlocal, tile13), LDS csr staging,
//      degree-balancing perm ----
__global__ __launch_bounds__(256) void bucket_fill(const int* __restrict__ tmpArr,
                                                   const int* __restrict__ bbase,
                                                   unsigned short* __restrict__ offs2,
                                                   float* __restrict__ dinv,
                                                   int* __restrict__ csr,
                                                   unsigned char* __restrict__ perm) {
    __shared__ int hist[256 * KPB]; // 16 KB
    __shared__ int part[256];
    __shared__ int lbuf[CSRCAP];    // 36 KB csr staging (53 KB total -> 3 blocks/CU)
    int b = blockIdx.x, t = threadIdx.x;
    int node0 = b << 8;
    int s = bbase[b], e = bbase[b + 1];
    int cnt = e - s;
    bool fits = cnt <= CSRCAP;
    for (int k = t; k < 256 * KPB; k += 256) hist[k] = 0;
    __syncthreads();
    for (int i = s + t; i < e; i += 256) {
        int en = tmpArr[i];
        int key = ((en & 255) << 4) | ((en >> 8) >> 14);
        atomicAdd(&hist[key], 1);
    }
    __syncthreads();
    // thread t == dest t: serial exclusive scan of its 16 key slots
    int base = t << 4;
    int ex[KPB];
    int sum = 0;
#pragma unroll
    for (int j = 0; j < KPB; j++) { ex[j] = sum; sum += hist[base + j]; }
    part[t] = sum;
    int nn = min(256, N_NODES - node0);
    if (t < nn) dinv[node0 + t] = rsqrtf((float)(sum + 1));
    // block exclusive scan over part
    int mine = sum;
    for (int off = 1; off < 256; off <<= 1) {
        __syncthreads();
        int a = (t >= off) ? part[t - off] : 0;
        __syncthreads();
        part[t] += a;
    }
    __syncthreads();
    int chunk0 = part[t] - mine; // exclusive prefix for this dest
#pragma unroll
    for (int j = 0; j < KPB; j++) hist[base + j] = chunk0 + ex[j];
    __syncthreads();
    // offs2: bucket-local u16 starts; slot 13 = dest end (slots 13..15 had 0 count)
    for (int k = t; k < 256 * KPB; k += 256)
        offs2[((size_t)b << 12) + k] = (unsigned short)hist[k];
    __syncthreads();
    // scatter into LDS window (coalesced stream-out), fallback to global if oversized
    for (int i = s + t; i < e; i += 256) {
        int en = tmpArr[i];
        int src = en >> 8;
        int key = ((en & 255) << 4) | (src >> 14);
        int p = atomicAdd(&hist[key], 1);
        if (fits) lbuf[p] = src; else csr[s + p] = src;
    }
    __syncthreads();
    if (fits)
        for (int i = t; i < cnt; i += 256) csr[s + i] = lbuf[i];
    // ---- degree-balancing permutation: counting sort dests by degree ----
    __syncthreads();
    part[t] = 0;
    __syncthreads();
    int dcl = min(sum, 255);
    atomicAdd(&part[dcl], 1);
    __syncthreads();
    int dcount = part[t];
    hist[t] = dcount;
    for (int off = 1; off < 256; off <<= 1) {
        __syncthreads();
        int a = (t >= off) ? hist[t - off] : 0;
        __syncthreads();
        hist[t] += a;
    }
    __syncthreads();
    part[t] = hist[t] - dcount;
    __syncthreads();
    int rank = atomicAdd(&part[dcl], 1);
    perm[(b << 8) + rank] = (unsigned char)t;
}

// ---- hs1[v] = (x[v] @ W1) * dinv[v], fp16, 32 B rows ----
__global__ __launch_bounds__(256) void gemm1(const float* __restrict__ x,
                                             const float* __restrict__ W1,
                                             const float* __restrict__ dinv,
                                             __half* __restrict__ hs1) {
    __shared__ float Wl[F_INC * F1];
    for (int i = threadIdx.x; i < F_INC * F1; i += 256) Wl[i] = W1[i];
    __syncthreads();
    int v = blockIdx.x * 256 + threadIdx.x;
    if (v >= N_NODES) return;
    float acc[F1];
#pragma unroll
    for (int f = 0; f < F1; f++) acc[f] = 0.f;
    const float4* xr = (const float4*)(x + (size_t)v * F_INC);
    for (int k4 = 0; k4 < F_INC / 4; k4++) {
        float4 xv = xr[k4];
        int kb = k4 * 4;
#pragma unroll
        for (int f = 0; f < F1; f++) {
            acc[f] += xv.x * Wl[(kb + 0) * F1 + f] + xv.y * Wl[(kb + 1) * F1 + f] +
                      xv.z * Wl[(kb + 2) * F1 + f] + xv.w * Wl[(kb + 3) * F1 + f];
        }
    }
    float dv = dinv[v];
    int w[6];
#pragma unroll
    for (int j = 0; j < 6; j++) {
        __half2 p = __floats2half2_rn(acc[2 * j] * dv, acc[2 * j + 1] * dv);
        w[j] = *(int*)&p;
    }
    __half* rowp = hs1 + (size_t)v * HS1_STRIDE;
    ((int4*)rowp)[0] = make_int4(w[0], w[1], w[2], w[3]);
    ((int2*)rowp)[2] = make_int2(w[4], w[5]);
}

__device__ __forceinline__ void acc_row1(float* acc, const __half* rowp) {
    int4 a = ((const int4*)rowp)[0];
    int2 b = ((const int2*)rowp)[2];
    int ws[6] = {a.x, a.y, a.z, a.w, b.x, b.y};
#pragma unroll
    for (int j = 0; j < 6; j++) {
        float2 t = __half22float2(*(__half2*)&ws[j]);
        acc[2 * j] += t.x;
        acc[2 * j + 1] += t.y;
    }
}

__device__ __forceinline__ void acc_row2(float* acc, const __half* rowp) {
    int4 a = ((const int4*)rowp)[0];
    int4 b = ((const int4*)rowp)[1];
    int4 c = ((const int4*)rowp)[2];
    int ws[12] = {a.x, a.y, a.z, a.w, b.x, b.y, b.z, b.w, c.x, c.y, c.z, c.w};
#pragma unroll
    for (int j = 0; j < 12; j++) {
        float2 t = __half22float2(*(__half2*)&ws[j]);
        acc[2 * j] += t.x;
        acc[2 * j + 1] += t.y;
    }
}

// ---- layer-1 aggregate: barrier-free walk (R7 structure), finer 1 MB tiles ----
__global__ __launch_bounds__(256, 3) void agg1(const __half* __restrict__ hs1,
                                               const unsigned short* __restrict__ offs2,
                                               const int* __restrict__ csr,
                                               const int* __restrict__ bbase,
                                               const float* __restrict__ dinv,
                                               const unsigned char* __restrict__ perm,
                                               const float* __restrict__ W2,
                                               const float* __restrict__ b1,
                                               __half* __restrict__ hs2) {
    __shared__ float Wl[F1 * F2];
    __shared__ float bl[F1];
    int t = threadIdx.x, b = blockIdx.x;
    for (int i = t; i < F1 * F2; i += 256) Wl[i] = W2[i];
    if (t < F1) bl[t] = b1[t];
    __syncthreads();
    int t2 = perm[(b << 8) + t]; // lanes get degree-similar dests
    int v = (b << 8) + t2;
    bool valid = v < N_NODES;
    int bb = bbase[b];
    float acc[F1];
#pragma unroll
    for (int f = 0; f < F1; f++) acc[f] = 0.f;
    if (valid) acc_row1(acc, hs1 + (size_t)v * HS1_STRIDE); // self loop
    const unsigned short* op2 = offs2 + (((size_t)b << 12) + ((size_t)t2 << 4));
    int i = bb + op2[0], e = bb + op2[13]; // contiguous, tile-sorted (ascending src)
    for (; i < e && (i & 3); ++i)
        acc_row1(acc, hs1 + (size_t)csr[i] * HS1_STRIDE);
    for (; i + 8 <= e; i += 8) {
        int4 ca = *(const int4*)(csr + i);
        int4 cb = *(const int4*)(csr + i + 4);
        int idx[8] = {ca.x, ca.y, ca.z, ca.w, cb.x, cb.y, cb.z, cb.w};
        int4 ra[8]; int2 rb[8];
#pragma unroll
        for (int u = 0; u < 8; u++) {
            const __half* rp = hs1 + (size_t)idx[u] * HS1_STRIDE;
            ra[u] = ((const int4*)rp)[0];
            rb[u] = ((const int2*)rp)[2];
        }
#pragma unroll
        for (int u = 0; u < 8; u++) {
            int ws[6] = {ra[u].x, ra[u].y, ra[u].z, ra[u].w, rb[u].x, rb[u].y};
#pragma unroll
            for (int j = 0; j < 6; j++) {
                float2 f2 = __half22float2(*(__half2*)&ws[j]);
                acc[2 * j] += f2.x;
                acc[2 * j + 1] += f2.y;
            }
        }
    }
    if (i + 4 <= e) {
        int4 ca = *(const int4*)(csr + i);
        int idx[4] = {ca.x, ca.y, ca.z, ca.w};
        int4 ra[4]; int2 rb[4];
#pragma unroll
        for (int u = 0; u < 4; u++) {
            const __half* rp = hs1 + (size_t)idx[u] * HS1_STRIDE;
            ra[u] = ((const int4*)rp)[0];
            rb[u] = ((const int2*)rp)[2];
        }
#pragma unroll
        for (int u = 0; u < 4; u++) {
            int ws[6] = {ra[u].x, ra[u].y, ra[u].z, ra[u].w, rb[u].x, rb[u].y};
#pragma unroll
            for (int j = 0; j < 6; j++) {
                float2 f2 = __half22float2(*(__half2*)&ws[j]);
                acc[2 * j] += f2.x;
                acc[2 * j + 1] += f2.y;
            }
        }
        i += 4;
    }
    for (; i < e; ++i)
        acc_row1(acc, hs1 + (size_t)csr[i] * HS1_STRIDE);
    if (!valid) return;
    float dv = dinv[v];
    float o[F1];
#pragma unroll
    for (int f = 0; f < F1; f++) o[f] = fmaxf(dv * acc[f] + bl[f], 0.f);
    float h2[F2];
#pragma unroll
    for (int g = 0; g < F2; g++) {
        float sum = 0.f;
#pragma unroll
        for (int f = 0; f < F1; f++) sum += o[f] * Wl[f * F2 + g];
        h2[g] = dv * sum;
    }
    int w[12];
#pragma unroll
    for (int j = 0; j < 12; j++) {
        __half2 p = __floats2half2_rn(h2[2 * j], h2[2 * j + 1]);
        w[j] = *(int*)&p;
    }
    int4* op = (int4*)(hs2 + (size_t)v * HS2_STRIDE);
    op[0] = make_int4(w[0], w[1], w[2], w[3]);
    op[1] = make_int4(w[4], w[5], w[6], w[7]);
    op[2] = make_int4(w[8], w[9], w[10], w[11]);
}

// ---- layer-2 aggregate: barrier-free walk + relu + fc1(relu) + fc2 ----
__global__ __launch_bounds__(256, 3) void agg2(const __half* __restrict__ hs2,
                                               const unsigned short* __restrict__ offs2,
                                               const int* __restrict__ csr,
                                               const int* __restrict__ bbase,
                                               const float* __restrict__ dinv,
                                               const unsigned char* __restrict__ perm,
                                               const float* __restrict__ b2,
                                               const float* __restrict__ Wf1,
                                               const float* __restrict__ bf1,
                                               const float* __restrict__ Wf2,
                                               const float* __restrict__ bf2,
                                               float* __restrict__ out) {
    __shared__ float W1s[F2 * 32];
    __shared__ float W2s[32 * 2];
    __shared__ float b2s[F2], b1s[32], bfs[2];
    int t = threadIdx.x, b = blockIdx.x;
    for (int i = t; i < F2 * 32; i += 256) W1s[i] = Wf1[i];
    if (t < 64) W2s[t] = Wf2[t];
    if (t < F2) b2s[t] = b2[t];
    if (t < 32) b1s[t] = bf1[t];
    if (t < 2) bfs[t] = bf2[t];
    __syncthreads();
    int t2 = perm[(b << 8) + t];
    int v = (b << 8) + t2;
    bool valid = v < N_NODES;
    int bb = bbase[b];
    float acc[F2];
#pragma unroll
    for (int f = 0; f < F2; f++) acc[f] = 0.f;
    if (valid) acc_row2(acc, hs2 + (size_t)v * HS2_STRIDE); // self loop
    const unsigned short* op2 = offs2 + (((size_t)b << 12) + ((size_t)t2 << 4));
    int i = bb + op2[0], e = bb + op2[13];
    for (; i < e && (i & 3); ++i)
        acc_row2(acc, hs2 + (size_t)csr[i] * HS2_STRIDE);
    for (; i + 8 <= e; i += 8) {
        int4 ca = *(const int4*)(csr + i);
        int4 cb = *(const int4*)(csr + i + 4);
        int ia[4] = {ca.x, ca.y, ca.z, ca.w};
        int ib[4] = {cb.x, cb.y, cb.z, cb.w};
        int4 a0[4], a1[4], a2[4];
        int4 b0[4], b1v[4], b2v[4];
#pragma unroll
        for (int u = 0; u < 4; u++) {
            const int4* rp = (const int4*)(hs2 + (size_t)ia[u] * HS2_STRIDE);
            a0[u] = rp[0]; a1[u] = rp[1]; a2[u] = rp[2];
        }
#pragma unroll
        for (int u = 0; u < 4; u++) {
            const int4* rp = (const int4*)(hs2 + (size_t)ib[u] * HS2_STRIDE);
            b0[u] = rp[0]; b1v[u] = rp[1]; b2v[u] = rp[2];
        }
#pragma unroll
        for (int u = 0; u < 4; u++) {
            int ws[12] = {a0[u].x, a0[u].y, a0[u].z, a0[u].w,
                          a1[u].x, a1[u].y, a1[u].z, a1[u].w,
                          a2[u].x, a2[u].y, a2[u].z, a2[u].w};
#pragma unroll
            for (int j = 0; j < 12; j++) {
                float2 f2 = __half22float2(*(__half2*)&ws[j]);
                acc[2 * j] += f2.x;
                acc[2 * j + 1] += f2.y;
            }
        }
#pragma unroll
        for (int u = 0; u < 4; u++) {
            int ws[12] = {b0[u].x, b0[u].y, b0[u].z, b0[u].w,
                          b1v[u].x, b1v[u].y, b1v[u].z, b1v[u].w,
                          b2v[u].x, b2v[u].y, b2v[u].z, b2v[u].w};
#pragma unroll
            for (int j = 0; j < 12; j++) {
                float2 f2 = __half22float2(*(__half2*)&ws[j]);
                acc[2 * j] += f2.x;
                acc[2 * j + 1] += f2.y;
            }
        }
    }
    if (i + 4 <= e) {
        int4 ca = *(const int4*)(csr + i);
        int ia[4] = {ca.x, ca.y, ca.z, ca.w};
        int4 a0[4], a1[4], a2[4];
#pragma unroll
        for (int u = 0; u < 4; u++) {
            const int4* rp = (const int4*)(hs2 + (size_t)ia[u] * HS2_STRIDE);
            a0[u] = rp[0]; a1[u] = rp[1]; a2[u] = rp[2];
        }
#pragma unroll
        for (int u = 0; u < 4; u++) {
            int ws[12] = {a0[u].x, a0[u].y, a0[u].z, a0[u].w,
                          a1[u].x, a1[u].y, a1[u].z, a1[u].w,
                          a2[u].x, a2[u].y, a2[u].z, a2[u].w};
#pragma unroll
            for (int j = 0; j < 12; j++) {
                float2 f2 = __half22float2(*(__half2*)&ws[j]);
                acc[2 * j] += f2.x;
                acc[2 * j + 1] += f2.y;
            }
        }
        i += 4;
    }
    for (; i < e; ++i)
        acc_row2(acc, hs2 + (size_t)csr[i] * HS2_STRIDE);
    if (!valid) return;
    float dv = dinv[v];
    float o2[F2];
#pragma unroll
    for (int f = 0; f < F2; f++) o2[f] = fmaxf(dv * acc[f] + b2s[f], 0.f);
    float c0 = bfs[0], c1 = bfs[1];
#pragma unroll
    for (int g = 0; g < 32; g++) {
        float sum = b1s[g];
#pragma unroll
        for (int f = 0; f < F2; f++) sum += o2[f] * W1s[f * 32 + g];
        sum = fmaxf(sum, 0.f);
        c0 += sum * W2s[2 * g + 0];
        c1 += sum * W2s[2 * g + 1];
    }
    float2 r; r.x = c0; r.y = c1;
    ((float2*)out)[v] = r;
}

extern "C" void kernel_launch(void* const* d_in, const int* in_sizes, int n_in,
                              void* d_out, int out_size, void* d_ws, size_t ws_size,
                              hipStream_t stream) {
    const float* x = (const float*)d_in[0];
    const int* erow = (const int*)d_in[1]; // edge_index delivered as int32
    const int* ecol = erow + N_EDGES;
    const float* W1 = (const float*)d_in[2];
    const float* b1 = (const float*)d_in[3];
    const float* W2 = (const float*)d_in[4];
    const float* b2 = (const float*)d_in[5];
    const float* Wf1 = (const float*)d_in[6];
    const float* bf1 = (const float*)d_in[7];
    const float* Wf2 = (const float*)d_in[8];
    const float* bf2 = (const float*)d_in[9];
    float* out = (float*)d_out;

    char* w = (char*)d_ws;
    auto alloc = [&](size_t bytes) -> char* {
        char* p = w;
        w += (bytes + 255) / 256 * 256;
        return p;
    };
    int* bcnt = (int*)alloc((size_t)NBUCK * 4);
    int* bbase = (int*)alloc((size_t)(NBUCK + 1) * 4);
    int* hist2d = (int*)alloc((size_t)NBLK * NBUCK * 4); // 2.45 MB
    float* dinv = (float*)alloc((size_t)N_NODES * 4);
    unsigned char* perm = (unsigned char*)alloc((size_t)NBUCK * 256); // 200 KB
    unsigned short* offs2 = (unsigned short*)alloc((size_t)NBUCK * 256 * KPB * 2 + 256); // 6.4 MB (+pad)
    int* csr = (int*)alloc((size_t)N_EDGES * 4); // 25.6 MB
    // union: tmpArr (25.6 MB) dead after bucket_fill; hs1 (6.4) + hs2 (12.8) after
    size_t hs1_bytes = (size_t)N_NODES * HS1_STRIDE * 2;
    char* uni = alloc((size_t)N_EDGES * 4);
    int* tmpArr = (int*)uni;
    __half* hs1 = (__half*)uni;
    __half* hs2 = (__half*)(uni + hs1_bytes);

    const int nodeGrid = (N_NODES + 255) / 256;

    hipLaunchKernelGGL(hist_pass, dim3(NBLK), dim3(1024), 0, stream, ecol, hist2d);
    hipLaunchKernelGGL(colscan, dim3(NBUCK), dim3(256), 0, stream, hist2d, bcnt);
    hipLaunchKernelGGL(bucket_scan, dim3(1), dim3(1024), 0, stream, bcnt, bbase);
    hipLaunchKernelGGL(scatter2, dim3(NBLK), dim3(1024), 0, stream, erow, ecol, bbase, hist2d, bcnt, tmpArr);
    hipLaunchKernelGGL(bucket_fill, dim3(NBUCK), dim3(256), 0, stream, tmpArr, bbase, offs2, dinv, csr, perm);
    hipLaunchKernelGGL(gemm1, dim3(nodeGrid), dim3(256), 0, stream, x, W1, dinv, hs1);
    hipLaunchKernelGGL(agg1, dim3(NBUCK), dim3(256), 0, stream,
                       hs1, offs2, csr, bbase, dinv, perm, W2, b1, hs2);
    hipLaunchKernelGGL(agg2, dim3(NBUCK), dim3(256), 0, stream,
                       hs2, offs2, csr, bbase, dinv, perm, b2, Wf1, bf1, Wf2, bf2, out);
}